// Round 16
// baseline (77.176 us; speedup 1.0000x reference)
//
#include <hip/hip_runtime.h>

#define IC 128
#define OC 256
#define RR 64
#define CCOLS 64
#define HO 62
#define WO 62
#define NB 16

// ws layout:
//   T    : x-major bf16 image  T[b][y][ck16][x 64][8c] = 16 MB (+256 pad)
//   W9Tf : fragment-major bf16 weights (R8 layout), 589824 B
//   bias : 256 floats
#define T_BYTES (NB * 64 * 16 * 64 * 16)        // 16777216
#define T_PAD   256
#define W9T_BYTES (9 * OC * IC * 2)             // 589824
#define CHUNK_STRIDE 8192                       // 8 ocgroups * 64 lanes * 16 B

typedef __bf16 bf16x8 __attribute__((ext_vector_type(8)));
typedef float f32x16 __attribute__((ext_vector_type(16)));

__device__ __forceinline__ unsigned short f2bf(float f) {
    unsigned u = __builtin_bit_cast(unsigned, f);
    u += 0x7FFFu + ((u >> 16) & 1u);   // round-to-nearest-even
    return (unsigned short)(u >> 16);
}

// Transpose images [b][c][y][x] fp32 -> T[b][y][ck16][x][8c] bf16.
// Thread t: x = t&63, ck16 = (t>>6) + 4h. Reads wave-coalesced 256 B per
// channel; writes 1 KB contiguous per (wave, ck16). One-time ~48 MB pass.
__global__ void transpose_img(const float* __restrict__ images,
                              unsigned char* __restrict__ T) {
    const int y = blockIdx.x;
    const int b = blockIdx.y;
    const int xs = threadIdx.x & 63;
    const int ckq = threadIdx.x >> 6;           // 0..3
    const float* __restrict__ imgb = images + (size_t)b * (IC * RR * CCOLS);
    unsigned char* __restrict__ trow = T + (((size_t)b * 64 + y) * 16) * 1024;
    #pragma unroll
    for (int h = 0; h < 4; ++h) {
        const int ck = ckq + 4 * h;             // 0..15
        const int c0 = ck * 8;
        const float* __restrict__ p = imgb + (size_t)c0 * (RR * CCOLS) + y * CCOLS + xs;
        unsigned v0, v1, v2, v3;
        v0 = (unsigned)f2bf(p[0])              | ((unsigned)f2bf(p[RR * CCOLS])     << 16);
        v1 = (unsigned)f2bf(p[2 * RR * CCOLS]) | ((unsigned)f2bf(p[3 * RR * CCOLS]) << 16);
        v2 = (unsigned)f2bf(p[4 * RR * CCOLS]) | ((unsigned)f2bf(p[5 * RR * CCOLS]) << 16);
        v3 = (unsigned)f2bf(p[6 * RR * CCOLS]) | ((unsigned)f2bf(p[7 * RR * CCOLS]) << 16);
        *(uint4*)(trow + ck * 1024 + xs * 16) = make_uint4(v0, v1, v2, v3);
    }
}

// prep: blocks 0..OC-1 scatter weights; block OC densifies the bias.
__global__ void prep_weights(const float* __restrict__ wv,
                             const int* __restrict__ iwi,
                             const int* __restrict__ flen,
                             const int* __restrict__ sp,
                             unsigned char* __restrict__ W9Tf,
                             const int* __restrict__ bias_index,
                             const float* __restrict__ bias_value,
                             float* __restrict__ bias_dense, int nbias) {
    if (blockIdx.x == OC) {
        int t = threadIdx.x;
        if (t < OC) bias_dense[t] = 0.f;
        __syncthreads();
        if (t < nbias) atomicAdd(&bias_dense[bias_index[t]], bias_value[t]);
        return;
    }
    const int oc = blockIdx.x;
    const int s = sp[oc];
    const int n = flen[oc];
    const int g = oc >> 5;
    for (int t = threadIdx.x; t < n; t += blockDim.x) {
        const int ix = iwi[s + t];          // c*4096 + ky*64 + kx
        const int c = ix >> 12;
        const int rem = ix & 4095;
        const int ky = rem >> 6, kx = rem & 63;
        const int kp = ky * 3 + kx;
        const int ck = c >> 4;
        const int khalf = (c >> 3) & 1;
        const int lane = (oc & 31) + (khalf << 5);
        const size_t off = (size_t)(kp * 8 + ck) * CHUNK_STRIDE +
                           g * 1024 + lane * 16 + (c & 7) * 2;
        *(unsigned short*)(W9Tf + off) = f2bf(wv[s + t]);
    }
}

// LDS-free conv. Block = one output row (b, y) x all 256 oc. 256 threads =
// 4 waves; wave w: 2 oc-groups {2w, 2w+1} x 64 x (2 n-tiles). Per K-chunk:
// 2 coalesced A-loads + 2 coalesced B-loads (from transposed global, L1/L2)
// + 4 independent MFMAs. No LDS, no barrier, no bank conflicts — R15's
// accounting showed the 1-read/MFMA LDS pipe commits ~37us/CU alone.
// All 4 waves read identical B addresses -> L1 sharing. Both streams
// prefetched 3 deep. ~68 VGPR + 64 AGPR -> 3 waves/SIMD.
__global__ __launch_bounds__(256, 3) void conv_mfma(
    const unsigned char* __restrict__ T,
    const unsigned char* __restrict__ W9Tf,
    const float* __restrict__ bias_dense,
    float* __restrict__ out)
{
    const int y = blockIdx.x;
    const int b = blockIdx.y;
    const int t = threadIdx.x;
    const int w = t >> 6;             // 0..3
    const int l = t & 63;
    const int lm = l & 31;            // m-row / n-col within frag
    const int lhi = l >> 5;           // k-half

    // lane's coalesced A bases for the wave's two oc-groups
    const unsigned char* __restrict__ pA0 = W9Tf + (2 * w + 0) * 1024 + l * 16;
    const unsigned char* __restrict__ pA1 = W9Tf + (2 * w + 1) * 1024 + l * 16;
    // lane's B base: row (b,y), k-half lhi, column lm
    const unsigned char* __restrict__ pB =
        T + (((size_t)b * 64 + y) * 16 + lhi) * 1024 + lm * 16;

    // B reader for chunk idx (compile-time ky/kx/ci under full unroll):
    // addr = pB + ky*16384 + ci*2048 + kx*16 + n*512   (x = n*32+lm+kx;
    // x up to 65 runs into the next ck16 row / +64B tail pad — those lanes'
    // outputs are never stored).
    auto readB = [&](int idx, bf16x8& b0, bf16x8& b1) {
        const int kp = idx >> 3, ci = idx & 7;
        const int ky = kp / 3, kx = kp % 3;
        const unsigned char* __restrict__ p = pB + ky * 16384 + ci * 2048 + kx * 16;
        b0 = *(const bf16x8*)(p);
        b1 = *(const bf16x8*)(p + 512);
    };

    // prologue: prefetch A and B chunks 0..2
    bf16x8 a0C  = *(const bf16x8*)(pA0);
    bf16x8 a1C  = *(const bf16x8*)(pA1);
    bf16x8 a0N1 = *(const bf16x8*)(pA0 + CHUNK_STRIDE);
    bf16x8 a1N1 = *(const bf16x8*)(pA1 + CHUNK_STRIDE);
    bf16x8 a0N2 = *(const bf16x8*)(pA0 + 2 * CHUNK_STRIDE);
    bf16x8 a1N2 = *(const bf16x8*)(pA1 + 2 * CHUNK_STRIDE);
    bf16x8 b0C, b1C, b0N1, b1N1, b0N2, b1N2;
    readB(0, b0C, b1C);
    readB(1, b0N1, b1N1);
    readB(2, b0N2, b1N2);

    // named accumulators c<m><n> (static indexing -> no scratch; rule #20)
    f32x16 c00 = {}, c01 = {}, c10 = {}, c11 = {};

    #pragma unroll
    for (int idx = 0; idx < 72; ++idx) {
        bf16x8 a0N3, a1N3, b0N3, b1N3;
        if (idx + 3 < 72) {
            a0N3 = *(const bf16x8*)(pA0 + (size_t)(idx + 3) * CHUNK_STRIDE);
            a1N3 = *(const bf16x8*)(pA1 + (size_t)(idx + 3) * CHUNK_STRIDE);
            readB(idx + 3, b0N3, b1N3);
        }

        c00 = __builtin_amdgcn_mfma_f32_32x32x16_bf16(a0C, b0C, c00, 0, 0, 0);
        c10 = __builtin_amdgcn_mfma_f32_32x32x16_bf16(a1C, b0C, c10, 0, 0, 0);
        c01 = __builtin_amdgcn_mfma_f32_32x32x16_bf16(a0C, b1C, c01, 0, 0, 0);
        c11 = __builtin_amdgcn_mfma_f32_32x32x16_bf16(a1C, b1C, c11, 0, 0, 0);

        a0C = a0N1; a0N1 = a0N2;                 // SSA-renamed, no copies
        a1C = a1N1; a1N1 = a1N2;
        b0C = b0N1; b0N1 = b0N2;
        b1C = b1N1; b1N1 = b1N2;
        if (idx + 3 < 72) { a0N2 = a0N3; a1N2 = a1N3; b0N2 = b0N3; b1N2 = b1N3; }
    }

    // ---- epilogue: bias + store ----
    // C/D 32x32: col = lane&31, row = (reg&3) + 8*(reg>>2) + 4*(lane>>5)
    #pragma unroll
    for (int m = 0; m < 2; ++m) {
        const int ocw = (2 * w + m) * 32;
        const f32x16 d0 = m ? c10 : c00;
        const f32x16 d1 = m ? c11 : c01;
        #pragma unroll
        for (int r = 0; r < 16; ++r) {
            const int oc = ocw + (r & 3) + 8 * (r >> 2) + 4 * lhi;
            const float bv = bias_dense[oc];
            const size_t ob = (((size_t)b * OC + oc) * HO + y) * WO;
            out[ob + lm] = d0[r] + bv;             // x = lm < 62 always
            if (lm < 30)
                out[ob + 32 + lm] = d1[r] + bv;    // x = 32+lm, clip at 62
        }
    }
}

extern "C" void kernel_launch(void* const* d_in, const int* in_sizes, int n_in,
                              void* d_out, int out_size, void* d_ws, size_t ws_size,
                              hipStream_t stream) {
    const float* images             = (const float*)d_in[0];
    const float* weight_value       = (const float*)d_in[1];
    const int*   image_weight_index = (const int*)d_in[2];
    const int*   filter_lengths     = (const int*)d_in[3];
    const int*   start_points       = (const int*)d_in[4];
    const int*   bias_index         = (const int*)d_in[5];
    const float* bias_value         = (const float*)d_in[6];
    float* out = (float*)d_out;

    unsigned char* T    = (unsigned char*)d_ws;
    unsigned char* W9Tf = (unsigned char*)d_ws + T_BYTES + T_PAD;
    float* bias_dense   = (float*)(W9Tf + W9T_BYTES);

    hipMemsetAsync(W9Tf, 0, W9T_BYTES, stream);
    transpose_img<<<dim3(64, NB), 256, 0, stream>>>(images, T);
    prep_weights<<<OC + 1, 256, 0, stream>>>(weight_value, image_weight_index,
                                             filter_lengths, start_points, W9Tf,
                                             bias_index, bias_value, bias_dense,
                                             in_sizes[5]);

    dim3 grid(HO, NB);
    conv_mfma<<<grid, 256, 0, stream>>>(T, W9Tf, bias_dense, out);
}